// Round 15
// baseline (484.607 us; speedup 1.0000x reference)
//
#include <hip/hip_runtime.h>

#define N_NODES   50000
#define N_EDGES   800000
#define NUM_GRAPHS 64
#define D         128
#define SLOPE     0.01

typedef double d4 __attribute__((ext_vector_type(4)));

__device__ __forceinline__ double dleaky(double v) { return v >= 0.0 ? v : SLOPE * v; }

// ---------------- zero ----------------
__global__ void zero_kernel(int* __restrict__ p, int n) {
    int i = blockIdx.x * blockDim.x + threadIdx.x;
    if (i < n) p[i] = 0;
}

// ---------------- degree histogram (by col) ----------------
__global__ void hist_kernel(const int* __restrict__ col, int* __restrict__ hist, int E) {
    int e = blockIdx.x * blockDim.x + threadIdx.x;
    if (e < E) atomicAdd(&hist[col[e]], 1);
}

// ---------------- multi-block exclusive scan (3 kernels); scan1 also emits dinv ----------------
__global__ __launch_bounds__(256) void scan1(const int* __restrict__ hist,
                                             int* __restrict__ start,
                                             int* __restrict__ bsum,
                                             double* __restrict__ dinvd, int n) {
    __shared__ int tmp[256];
    const int tid = threadIdx.x;
    int base = blockIdx.x * 1024 + tid * 4;
    int v[4]; int s = 0;
#pragma unroll
    for (int i = 0; i < 4; ++i) {
        int idx = base + i;
        v[i] = (idx < n) ? hist[idx] : 0;
        s += v[i];
        if (idx < n) dinvd[idx] = 1.0 / sqrt((double)v[i] + 1.0);
    }
    tmp[tid] = s;
    __syncthreads();
    for (int off = 1; off < 256; off <<= 1) {
        int t = (tid >= off) ? tmp[tid - off] : 0;
        __syncthreads();
        tmp[tid] += t;
        __syncthreads();
    }
    int run = tmp[tid] - s;
    if (tid == 255) bsum[blockIdx.x] = tmp[255];
#pragma unroll
    for (int i = 0; i < 4; ++i) { int idx = base + i; if (idx < n) start[idx] = run; run += v[i]; }
}

__global__ __launch_bounds__(256) void scan2(int* __restrict__ bsum, int nb,
                                             int* __restrict__ start, int n) {
    __shared__ int tmp[256];
    const int tid = threadIdx.x;
    int v = (tid < nb) ? bsum[tid] : 0;
    tmp[tid] = v;
    __syncthreads();
    for (int off = 1; off < 256; off <<= 1) {
        int t = (tid >= off) ? tmp[tid - off] : 0;
        __syncthreads();
        tmp[tid] += t;
        __syncthreads();
    }
    if (tid < nb) bsum[tid] = tmp[tid] - v;
    if (tid == 255) start[n] = tmp[255];
}

__global__ __launch_bounds__(256) void scan3(int* __restrict__ start, int* __restrict__ cursor,
                                             const int* __restrict__ bsum, int n) {
    int off = bsum[blockIdx.x];
    int base = blockIdx.x * 1024 + threadIdx.x * 4;
#pragma unroll
    for (int i = 0; i < 4; ++i) {
        int j = base + i;
        if (j < n) { int v = start[j] + off; start[j] = v; cursor[j] = v; }
    }
}

// ---------------- CSR build: scatter source rows, sorted by col ----------------
__global__ void build_kernel(const int* __restrict__ row, const int* __restrict__ col,
                             int* __restrict__ cursor, int* __restrict__ srcrow, int E) {
    int e = blockIdx.x * blockDim.x + threadIdx.x;
    if (e >= E) return;
    int p = atomicAdd(&cursor[col[e]], 1);
    srcrow[p] = row[e];
}

// ---------------- graph boundaries from sorted batch: gstart[65] ----------------
__global__ void gbound_kernel(const int* __restrict__ batch, int* __restrict__ gstart, int n) {
    int i = blockIdx.x * blockDim.x + threadIdx.x;
    if (i >= n) return;
    int b = batch[i];
    int prev = (i == 0) ? -1 : batch[i - 1];
    for (int g = prev + 1; g <= b; ++g) gstart[g] = i;
    if (i == n - 1) {
        for (int g = b + 1; g <= NUM_GRAPHS; ++g) gstart[g] = n;
    }
}

// ---------------- GEMM via v_mfma_f64_16x16x4: C = A @ W, optional prescale ----------------
// Both A and W chunks are register-prefetched; between barriers only ds_writes remain,
// and next-chunk global loads issue under the MFMA shadow. LDS 21 KB.
__global__ __launch_bounds__(256, 4) void gemm128_mfma(const float* __restrict__ A,
                                                       const float* __restrict__ W,
                                                       float* __restrict__ C, int M, int act,
                                                       const double* __restrict__ scale) {
    __shared__ float As[32][36];
    __shared__ float Ws[32][129];
    const int tid  = threadIdx.x;
    const int lane = tid & 63;
    const int wid  = tid >> 6;
    const int wrow = wid >> 1;
    const int wcol = wid & 1;
    const int rowBase = blockIdx.x * 32;

    d4 acc0 = {0.0, 0.0, 0.0, 0.0};
    d4 acc1 = {0.0, 0.0, 0.0, 0.0};
    d4 acc2 = {0.0, 0.0, 0.0, 0.0};
    d4 acc3 = {0.0, 0.0, 0.0, 0.0};

    const int lr = tid >> 3;          // 0..31 A row
    const int lc = (tid & 7) * 4;     // 0..28 A cols (float4)
    const int wr = tid & 31;          // 0..31 W row in chunk
    const int wc = (tid >> 5) * 16;   // 0..112 W cols

    const int growA = rowBase + lr;
    const bool haveA = (growA < M);

    float4 a0 = make_float4(0.f, 0.f, 0.f, 0.f);
    if (haveA) a0 = *reinterpret_cast<const float4*>(A + (size_t)growA * D + lc);
    float4 wreg[4];
#pragma unroll
    for (int i = 0; i < 4; ++i)
        wreg[i] = *reinterpret_cast<const float4*>(W + (size_t)wr * D + wc + 4 * i);

    const int arow = wrow * 16 + (lane & 15);
    const int asub = lane >> 4;
    const int bcol = wcol * 64 + (lane & 15);

    for (int kc = 0; kc < 128; kc += 32) {
        *reinterpret_cast<float4*>(&As[lr][lc]) = a0;
#pragma unroll
        for (int i = 0; i < 4; ++i)
            *reinterpret_cast<float4*>(&Ws[wr][wc + 4 * i]) = wreg[i];
        __syncthreads();

        if (kc + 32 < 128) {
            if (haveA)
                a0 = *reinterpret_cast<const float4*>(A + (size_t)growA * D + (kc + 32) + lc);
#pragma unroll
            for (int i = 0; i < 4; ++i)
                wreg[i] = *reinterpret_cast<const float4*>(W + (size_t)(kc + 32 + wr) * D + wc + 4 * i);
        }

#pragma unroll
        for (int kk = 0; kk < 8; ++kk) {
            double av = (double)As[arow][kk * 4 + asub];
            double b0 = (double)Ws[kk * 4 + asub][bcol +  0];
            double b1 = (double)Ws[kk * 4 + asub][bcol + 16];
            double b2 = (double)Ws[kk * 4 + asub][bcol + 32];
            double b3 = (double)Ws[kk * 4 + asub][bcol + 48];
            acc0 = __builtin_amdgcn_mfma_f64_16x16x4f64(av, b0, acc0, 0, 0, 0);
            acc1 = __builtin_amdgcn_mfma_f64_16x16x4f64(av, b1, acc1, 0, 0, 0);
            acc2 = __builtin_amdgcn_mfma_f64_16x16x4f64(av, b2, acc2, 0, 0, 0);
            acc3 = __builtin_amdgcn_mfma_f64_16x16x4f64(av, b3, acc3, 0, 0, 0);
        }
        __syncthreads();
    }

    const int rbase = rowBase + wrow * 16 + 4 * (lane >> 4);
    const int cb = wcol * 64 + (lane & 15);
#pragma unroll
    for (int r = 0; r < 4; ++r) {
        int grow = rbase + r;
        if (grow < M) {
            double sc = scale ? scale[grow] : 1.0;
            double v0 = acc0[r], v1 = acc1[r], v2 = acc2[r], v3 = acc3[r];
            if (act) { v0 = dleaky(v0); v1 = dleaky(v1); v2 = dleaky(v2); v3 = dleaky(v3); }
            v0 *= sc; v1 *= sc; v2 *= sc; v3 *= sc;
            float* crow = C + (size_t)grow * D + cb;
            crow[ 0] = (float)v0;
            crow[16] = (float)v1;
            crow[32] = (float)v2;
            crow[48] = (float)v3;
        }
    }
}

// ---------------- fc1+fc2 fused: svec = leaky( leaky(A@Wfc1) . wfc2 ) ----------------
__global__ __launch_bounds__(256, 4) void gemm_fc(const float* __restrict__ A,
                                                  const float* __restrict__ W,
                                                  const float* __restrict__ wfc2,
                                                  double* __restrict__ svec, int M) {
    __shared__ float As[32][36];
    __shared__ float Ws[32][129];
    const int tid  = threadIdx.x;
    const int lane = tid & 63;
    const int wid  = tid >> 6;
    const int wrow = wid >> 1;
    const int wcol = wid & 1;
    const int rowBase = blockIdx.x * 32;

    d4 acc0 = {0.0, 0.0, 0.0, 0.0};
    d4 acc1 = {0.0, 0.0, 0.0, 0.0};
    d4 acc2 = {0.0, 0.0, 0.0, 0.0};
    d4 acc3 = {0.0, 0.0, 0.0, 0.0};

    const int lr = tid >> 3;
    const int lc = (tid & 7) * 4;
    const int wr = tid & 31;
    const int wc = (tid >> 5) * 16;

    const int growA = rowBase + lr;
    const bool haveA = (growA < M);

    float4 a0 = make_float4(0.f, 0.f, 0.f, 0.f);
    if (haveA) a0 = *reinterpret_cast<const float4*>(A + (size_t)growA * D + lc);
    float4 wreg[4];
#pragma unroll
    for (int i = 0; i < 4; ++i)
        wreg[i] = *reinterpret_cast<const float4*>(W + (size_t)wr * D + wc + 4 * i);

    const int arow = wrow * 16 + (lane & 15);
    const int asub = lane >> 4;
    const int bcol = wcol * 64 + (lane & 15);

    for (int kc = 0; kc < 128; kc += 32) {
        *reinterpret_cast<float4*>(&As[lr][lc]) = a0;
#pragma unroll
        for (int i = 0; i < 4; ++i)
            *reinterpret_cast<float4*>(&Ws[wr][wc + 4 * i]) = wreg[i];
        __syncthreads();

        if (kc + 32 < 128) {
            if (haveA)
                a0 = *reinterpret_cast<const float4*>(A + (size_t)growA * D + (kc + 32) + lc);
#pragma unroll
            for (int i = 0; i < 4; ++i)
                wreg[i] = *reinterpret_cast<const float4*>(W + (size_t)(kc + 32 + wr) * D + wc + 4 * i);
        }

#pragma unroll
        for (int kk = 0; kk < 8; ++kk) {
            double av = (double)As[arow][kk * 4 + asub];
            double b0 = (double)Ws[kk * 4 + asub][bcol +  0];
            double b1 = (double)Ws[kk * 4 + asub][bcol + 16];
            double b2 = (double)Ws[kk * 4 + asub][bcol + 32];
            double b3 = (double)Ws[kk * 4 + asub][bcol + 48];
            acc0 = __builtin_amdgcn_mfma_f64_16x16x4f64(av, b0, acc0, 0, 0, 0);
            acc1 = __builtin_amdgcn_mfma_f64_16x16x4f64(av, b1, acc1, 0, 0, 0);
            acc2 = __builtin_amdgcn_mfma_f64_16x16x4f64(av, b2, acc2, 0, 0, 0);
            acc3 = __builtin_amdgcn_mfma_f64_16x16x4f64(av, b3, acc3, 0, 0, 0);
        }
        __syncthreads();
    }

    // stage y = leaky(acc) into dead Ws LDS (local row = grow - rowBase)
    {
        const int lrow = wrow * 16 + 4 * (lane >> 4);
        const int cb = wcol * 64 + (lane & 15);
#pragma unroll
        for (int r = 0; r < 4; ++r) {
            int grow = rowBase + lrow + r;
            if (grow < M) {
                Ws[lrow + r][cb +  0] = (float)dleaky(acc0[r]);
                Ws[lrow + r][cb + 16] = (float)dleaky(acc1[r]);
                Ws[lrow + r][cb + 32] = (float)dleaky(acc2[r]);
                Ws[lrow + r][cb + 48] = (float)dleaky(acc3[r]);
            }
        }
    }
    __syncthreads();

    // fc2: wave wid reduces rows wid*8 .. wid*8+7
    const double wlo = (double)wfc2[lane];
    const double whi = (double)wfc2[lane + 64];
#pragma unroll
    for (int rr = 0; rr < 8; ++rr) {
        int lrow = wid * 8 + rr;
        int grow = rowBase + lrow;
        if (grow >= M) break;
        double part = (double)Ws[lrow][lane] * wlo + (double)Ws[lrow][lane + 64] * whi;
#pragma unroll
        for (int off = 32; off > 0; off >>= 1) part += __shfl_down(part, off, 64);
        if (lane == 0) svec[grow] = dleaky(part);
    }
}

// ---------------- aggregation over prescaled rows h' = dinv_r * h ----------------
__global__ __launch_bounds__(256) void agg_s(const float* __restrict__ hp,
                                             const int* __restrict__ srcrow,
                                             const int* __restrict__ start,
                                             const double* __restrict__ dinvd,
                                             float* __restrict__ out, int n) {
    int node = (int)((blockIdx.x * blockDim.x + threadIdx.x) >> 6);
    int lane = threadIdx.x & 63;
    if (node >= n) return;
    int s = start[node], e = start[node + 1];
    double dn = dinvd[node];
    const int f = lane * 2;
    float2 hs = *reinterpret_cast<const float2*>(hp + (size_t)node * D + f);
    double ax = 0.0, ay = 0.0;
    int p = s;
    for (; p + 16 <= e; p += 16) {
        int r[16]; float2 hv[16];
#pragma unroll
        for (int i = 0; i < 16; ++i) r[i] = srcrow[p + i];
#pragma unroll
        for (int i = 0; i < 16; ++i)
            hv[i] = *reinterpret_cast<const float2*>(hp + (size_t)r[i] * D + f);
#pragma unroll
        for (int i = 0; i < 16; ++i) { ax += (double)hv[i].x; ay += (double)hv[i].y; }
    }
    for (; p + 8 <= e; p += 8) {
        int r[8]; float2 hv[8];
#pragma unroll
        for (int i = 0; i < 8; ++i) r[i] = srcrow[p + i];
#pragma unroll
        for (int i = 0; i < 8; ++i)
            hv[i] = *reinterpret_cast<const float2*>(hp + (size_t)r[i] * D + f);
#pragma unroll
        for (int i = 0; i < 8; ++i) { ax += (double)hv[i].x; ay += (double)hv[i].y; }
    }
    for (; p < e; ++p) {
        int r = srcrow[p];
        float2 hv = *reinterpret_cast<const float2*>(hp + (size_t)r * D + f);
        ax += (double)hv.x; ay += (double)hv.y;
    }
    ax = dleaky((ax + (double)hs.x) * dn);
    ay = dleaky((ay + (double)hs.y) * dn);
    *reinterpret_cast<float2*>(out + (size_t)node * D + f) =
        make_float2((float)ax, (float)ay);
}

// ---------------- pool: block per graph over its contiguous node range ----------------
__global__ __launch_bounds__(256) void pool2(const double* __restrict__ s,
                                             const int* __restrict__ gstart,
                                             float* __restrict__ out) {
    __shared__ double lsum[256];
    const int g = blockIdx.x;
    const int tid = threadIdx.x;
    const int s0 = gstart[g], s1 = gstart[g + 1];
    double sum = 0.0;
    for (int i = s0 + tid; i < s1; i += 256) sum += s[i];
    lsum[tid] = sum;
    __syncthreads();
    for (int off = 128; off > 0; off >>= 1) {
        if (tid < off) lsum[tid] += lsum[tid + off];
        __syncthreads();
    }
    if (tid == 0) {
        int cnt = s1 - s0;
        out[g] = (float)(lsum[0] / (double)(cnt > 0 ? cnt : 1));
    }
}

extern "C" void kernel_launch(void* const* d_in, const int* in_sizes, int n_in,
                              void* d_out, int out_size, void* d_ws, size_t ws_size,
                              hipStream_t stream) {
    const float* x    = (const float*)d_in[0];
    const int*   eidx = (const int*)d_in[1];
    const int*   batch= (const int*)d_in[2];
    const float* W0   = (const float*)d_in[3];
    const float* W1   = (const float*)d_in[4];
    const float* W2   = (const float*)d_in[5];
    const float* Wfc1 = (const float*)d_in[6];
    const float* Wfc2 = (const float*)d_in[7];
    float* out = (float*)d_out;

    const int* erow = eidx;
    const int* ecol = eidx + N_EDGES;

    char* ws = (char*)d_ws;
    int*    hist   = (int*)   (ws + 0);
    int*    start  = (int*)   (ws + 200064);
    int*    cursor = (int*)   (ws + 400384);   // dead after build -> reused as gstart
    int*    bsum   = (int*)   (ws + 600448);
    double* dinvd  = (double*)(ws + 600704);
    int*    srcrow = (int*)   (ws + 1000704);
    double* svec   = (double*)(ws + 4200704);
    float*  bufA   = (float*) (ws + 4600832);
    float*  bufB   = (float*) (ws + 30200832);
    int*    gstart = cursor;

    zero_kernel<<<(N_NODES + 255) / 256, 256, 0, stream>>>(hist, N_NODES);
    hist_kernel<<<(N_EDGES + 255) / 256, 256, 0, stream>>>(ecol, hist, N_EDGES);

    const int NB = (N_NODES + 1023) / 1024;  // 49
    scan1<<<NB, 256, 0, stream>>>(hist, start, bsum, dinvd, N_NODES);
    scan2<<<1, 256, 0, stream>>>(bsum, NB, start, N_NODES);
    scan3<<<NB, 256, 0, stream>>>(start, cursor, bsum, N_NODES);

    build_kernel<<<(N_EDGES + 255) / 256, 256, 0, stream>>>(erow, ecol, cursor, srcrow, N_EDGES);
    gbound_kernel<<<(N_NODES + 255) / 256, 256, 0, stream>>>(batch, gstart, N_NODES);

    const int GEMM_GRID = (N_NODES + 31) / 32;   // 1563
    const int AGG_GRID  = (N_NODES + 3) / 4;     // 12500

    // layers 0..2: gemm writes prescaled h' = dinv_r * (h @ W); agg_s finishes
    gemm128_mfma<<<GEMM_GRID, 256, 0, stream>>>(x, W0, bufA, N_NODES, 0, dinvd);
    agg_s<<<AGG_GRID, 256, 0, stream>>>(bufA, srcrow, start, dinvd, bufB, N_NODES);
    gemm128_mfma<<<GEMM_GRID, 256, 0, stream>>>(bufB, W1, bufA, N_NODES, 0, dinvd);
    agg_s<<<AGG_GRID, 256, 0, stream>>>(bufA, srcrow, start, dinvd, bufB, N_NODES);
    gemm128_mfma<<<GEMM_GRID, 256, 0, stream>>>(bufB, W2, bufA, N_NODES, 0, dinvd);
    agg_s<<<AGG_GRID, 256, 0, stream>>>(bufA, srcrow, start, dinvd, bufB, N_NODES);

    // fc1 + fc2 fused: svec = leaky(leaky(h@Wfc1) . wfc2)
    gemm_fc<<<GEMM_GRID, 256, 0, stream>>>(bufB, Wfc1, Wfc2, svec, N_NODES);

    pool2<<<NUM_GRAPHS, 256, 0, stream>>>(svec, gstart, out);
}

// Round 16
// 434.330 us; speedup vs baseline: 1.1158x; 1.1158x over previous
//
#include <hip/hip_runtime.h>

#define N_NODES   50000
#define N_EDGES   800000
#define NUM_GRAPHS 64
#define D         128
#define SLOPE     0.01

typedef double d4 __attribute__((ext_vector_type(4)));

__device__ __forceinline__ double dleaky(double v) { return v >= 0.0 ? v : SLOPE * v; }

// ---------------- degree histogram (by col) ----------------
__global__ void hist_kernel(const int* __restrict__ col, int* __restrict__ hist, int E) {
    int e = blockIdx.x * blockDim.x + threadIdx.x;
    if (e < E) atomicAdd(&hist[col[e]], 1);
}

// ---------------- multi-block exclusive scan (3 kernels); scan1 also emits dinv ----------------
__global__ __launch_bounds__(256) void scan1(const int* __restrict__ hist,
                                             int* __restrict__ start,
                                             int* __restrict__ bsum,
                                             double* __restrict__ dinvd, int n) {
    __shared__ int tmp[256];
    const int tid = threadIdx.x;
    int base = blockIdx.x * 1024 + tid * 4;
    int v[4]; int s = 0;
#pragma unroll
    for (int i = 0; i < 4; ++i) {
        int idx = base + i;
        v[i] = (idx < n) ? hist[idx] : 0;
        s += v[i];
        if (idx < n) dinvd[idx] = 1.0 / sqrt((double)v[i] + 1.0);
    }
    tmp[tid] = s;
    __syncthreads();
    for (int off = 1; off < 256; off <<= 1) {
        int t = (tid >= off) ? tmp[tid - off] : 0;
        __syncthreads();
        tmp[tid] += t;
        __syncthreads();
    }
    int run = tmp[tid] - s;
    if (tid == 255) bsum[blockIdx.x] = tmp[255];
#pragma unroll
    for (int i = 0; i < 4; ++i) { int idx = base + i; if (idx < n) start[idx] = run; run += v[i]; }
}

__global__ __launch_bounds__(256) void scan2(int* __restrict__ bsum, int nb,
                                             int* __restrict__ start, int n) {
    __shared__ int tmp[256];
    const int tid = threadIdx.x;
    int v = (tid < nb) ? bsum[tid] : 0;
    tmp[tid] = v;
    __syncthreads();
    for (int off = 1; off < 256; off <<= 1) {
        int t = (tid >= off) ? tmp[tid - off] : 0;
        __syncthreads();
        tmp[tid] += t;
        __syncthreads();
    }
    if (tid < nb) bsum[tid] = tmp[tid] - v;
    if (tid == 255) start[n] = tmp[255];
}

__global__ __launch_bounds__(256) void scan3(int* __restrict__ start, int* __restrict__ cursor,
                                             const int* __restrict__ bsum, int n) {
    int off = bsum[blockIdx.x];
    int base = blockIdx.x * 1024 + threadIdx.x * 4;
#pragma unroll
    for (int i = 0; i < 4; ++i) {
        int j = base + i;
        if (j < n) { int v = start[j] + off; start[j] = v; cursor[j] = v; }
    }
}

// ---------------- CSR build: scatter source rows, sorted by col ----------------
__global__ void build_kernel(const int* __restrict__ row, const int* __restrict__ col,
                             int* __restrict__ cursor, int* __restrict__ srcrow, int E) {
    int e = blockIdx.x * blockDim.x + threadIdx.x;
    if (e >= E) return;
    int p = atomicAdd(&cursor[col[e]], 1);
    srcrow[p] = row[e];
}

// ---------------- graph boundaries from sorted batch: gstart[65] ----------------
__global__ void gbound_kernel(const int* __restrict__ batch, int* __restrict__ gstart, int n) {
    int i = blockIdx.x * blockDim.x + threadIdx.x;
    if (i >= n) return;
    int b = batch[i];
    int prev = (i == 0) ? -1 : batch[i - 1];
    for (int g = prev + 1; g <= b; ++g) gstart[g] = i;
    if (i == n - 1) {
        for (int g = b + 1; g <= NUM_GRAPHS; ++g) gstart[g] = n;
    }
}

// ---------------- GEMM via v_mfma_f64_16x16x4: C = A @ W, optional prescale ----------------
// As f32 (4.6 KB, exact cvt at read), Ws f32 (16.5 KB); 21 KB -> 6 blocks/CU.
// (Round-14 form: A reg-prefetched, W global->LDS per chunk. W reg-prefetch
// variant spilled to scratch (r15: VGPR 40, 63 MB spill writes) -- do not revisit.)
__global__ __launch_bounds__(256, 6) void gemm128_mfma(const float* __restrict__ A,
                                                       const float* __restrict__ W,
                                                       float* __restrict__ C, int M, int act,
                                                       const double* __restrict__ scale) {
    __shared__ float As[32][36];
    __shared__ float Ws[32][129];
    const int tid  = threadIdx.x;
    const int lane = tid & 63;
    const int wid  = tid >> 6;
    const int wrow = wid >> 1;
    const int wcol = wid & 1;
    const int rowBase = blockIdx.x * 32;

    d4 acc0 = {0.0, 0.0, 0.0, 0.0};
    d4 acc1 = {0.0, 0.0, 0.0, 0.0};
    d4 acc2 = {0.0, 0.0, 0.0, 0.0};
    d4 acc3 = {0.0, 0.0, 0.0, 0.0};

    const int lr = tid >> 3;
    const int lc = (tid & 7) * 4;
    const int wr = tid & 31;
    const int wc = (tid >> 5) * 16;

    const int growA = rowBase + lr;
    const bool haveA = (growA < M);

    float4 a0 = make_float4(0.f, 0.f, 0.f, 0.f);
    if (haveA) a0 = *reinterpret_cast<const float4*>(A + (size_t)growA * D + lc);

    const int arow = wrow * 16 + (lane & 15);
    const int asub = lane >> 4;
    const int bcol = wcol * 64 + (lane & 15);

    for (int kc = 0; kc < 128; kc += 32) {
        *reinterpret_cast<float4*>(&As[lr][lc]) = a0;
        {
            const float4* src = reinterpret_cast<const float4*>(W + (size_t)(kc + wr) * D + wc);
#pragma unroll
            for (int i = 0; i < 4; ++i)
                *reinterpret_cast<float4*>(&Ws[wr][wc + 4 * i]) = src[i];
        }
        __syncthreads();

        if (kc + 32 < 128 && haveA)
            a0 = *reinterpret_cast<const float4*>(A + (size_t)growA * D + (kc + 32) + lc);

#pragma unroll
        for (int kk = 0; kk < 8; ++kk) {
            double av = (double)As[arow][kk * 4 + asub];
            double b0 = (double)Ws[kk * 4 + asub][bcol +  0];
            double b1 = (double)Ws[kk * 4 + asub][bcol + 16];
            double b2 = (double)Ws[kk * 4 + asub][bcol + 32];
            double b3 = (double)Ws[kk * 4 + asub][bcol + 48];
            acc0 = __builtin_amdgcn_mfma_f64_16x16x4f64(av, b0, acc0, 0, 0, 0);
            acc1 = __builtin_amdgcn_mfma_f64_16x16x4f64(av, b1, acc1, 0, 0, 0);
            acc2 = __builtin_amdgcn_mfma_f64_16x16x4f64(av, b2, acc2, 0, 0, 0);
            acc3 = __builtin_amdgcn_mfma_f64_16x16x4f64(av, b3, acc3, 0, 0, 0);
        }
        __syncthreads();
    }

    const int rbase = rowBase + wrow * 16 + 4 * (lane >> 4);
    const int cb = wcol * 64 + (lane & 15);
#pragma unroll
    for (int r = 0; r < 4; ++r) {
        int grow = rbase + r;
        if (grow < M) {
            double sc = scale ? scale[grow] : 1.0;
            double v0 = acc0[r], v1 = acc1[r], v2 = acc2[r], v3 = acc3[r];
            if (act) { v0 = dleaky(v0); v1 = dleaky(v1); v2 = dleaky(v2); v3 = dleaky(v3); }
            v0 *= sc; v1 *= sc; v2 *= sc; v3 *= sc;
            float* crow = C + (size_t)grow * D + cb;
            crow[ 0] = (float)v0;
            crow[16] = (float)v1;
            crow[32] = (float)v2;
            crow[48] = (float)v3;
        }
    }
}

// ---------------- fc1+fc2 fused: svec = leaky( leaky(A@Wfc1) . wfc2 ) ----------------
__global__ __launch_bounds__(256, 6) void gemm_fc(const float* __restrict__ A,
                                                  const float* __restrict__ W,
                                                  const float* __restrict__ wfc2,
                                                  double* __restrict__ svec, int M) {
    __shared__ float As[32][36];
    __shared__ float Ws[32][129];
    const int tid  = threadIdx.x;
    const int lane = tid & 63;
    const int wid  = tid >> 6;
    const int wrow = wid >> 1;
    const int wcol = wid & 1;
    const int rowBase = blockIdx.x * 32;

    d4 acc0 = {0.0, 0.0, 0.0, 0.0};
    d4 acc1 = {0.0, 0.0, 0.0, 0.0};
    d4 acc2 = {0.0, 0.0, 0.0, 0.0};
    d4 acc3 = {0.0, 0.0, 0.0, 0.0};

    const int lr = tid >> 3;
    const int lc = (tid & 7) * 4;
    const int wr = tid & 31;
    const int wc = (tid >> 5) * 16;

    const int growA = rowBase + lr;
    const bool haveA = (growA < M);

    float4 a0 = make_float4(0.f, 0.f, 0.f, 0.f);
    if (haveA) a0 = *reinterpret_cast<const float4*>(A + (size_t)growA * D + lc);

    const int arow = wrow * 16 + (lane & 15);
    const int asub = lane >> 4;
    const int bcol = wcol * 64 + (lane & 15);

    for (int kc = 0; kc < 128; kc += 32) {
        *reinterpret_cast<float4*>(&As[lr][lc]) = a0;
        {
            const float4* src = reinterpret_cast<const float4*>(W + (size_t)(kc + wr) * D + wc);
#pragma unroll
            for (int i = 0; i < 4; ++i)
                *reinterpret_cast<float4*>(&Ws[wr][wc + 4 * i]) = src[i];
        }
        __syncthreads();

        if (kc + 32 < 128 && haveA)
            a0 = *reinterpret_cast<const float4*>(A + (size_t)growA * D + (kc + 32) + lc);

#pragma unroll
        for (int kk = 0; kk < 8; ++kk) {
            double av = (double)As[arow][kk * 4 + asub];
            double b0 = (double)Ws[kk * 4 + asub][bcol +  0];
            double b1 = (double)Ws[kk * 4 + asub][bcol + 16];
            double b2 = (double)Ws[kk * 4 + asub][bcol + 32];
            double b3 = (double)Ws[kk * 4 + asub][bcol + 48];
            acc0 = __builtin_amdgcn_mfma_f64_16x16x4f64(av, b0, acc0, 0, 0, 0);
            acc1 = __builtin_amdgcn_mfma_f64_16x16x4f64(av, b1, acc1, 0, 0, 0);
            acc2 = __builtin_amdgcn_mfma_f64_16x16x4f64(av, b2, acc2, 0, 0, 0);
            acc3 = __builtin_amdgcn_mfma_f64_16x16x4f64(av, b3, acc3, 0, 0, 0);
        }
        __syncthreads();
    }

    // stage y = leaky(acc) into dead Ws LDS (local row = grow - rowBase)
    {
        const int lrow = wrow * 16 + 4 * (lane >> 4);
        const int cb = wcol * 64 + (lane & 15);
#pragma unroll
        for (int r = 0; r < 4; ++r) {
            int grow = rowBase + lrow + r;
            if (grow < M) {
                Ws[lrow + r][cb +  0] = (float)dleaky(acc0[r]);
                Ws[lrow + r][cb + 16] = (float)dleaky(acc1[r]);
                Ws[lrow + r][cb + 32] = (float)dleaky(acc2[r]);
                Ws[lrow + r][cb + 48] = (float)dleaky(acc3[r]);
            }
        }
    }
    __syncthreads();

    // fc2: wave wid reduces rows wid*8 .. wid*8+7
    const double wlo = (double)wfc2[lane];
    const double whi = (double)wfc2[lane + 64];
#pragma unroll
    for (int rr = 0; rr < 8; ++rr) {
        int lrow = wid * 8 + rr;
        int grow = rowBase + lrow;
        if (grow >= M) break;
        double part = (double)Ws[lrow][lane] * wlo + (double)Ws[lrow][lane + 64] * whi;
#pragma unroll
        for (int off = 32; off > 0; off >>= 1) part += __shfl_down(part, off, 64);
        if (lane == 0) svec[grow] = dleaky(part);
    }
}

// ---------------- aggregation over prescaled rows h' = dinv_r * h ----------------
__global__ __launch_bounds__(256) void agg_s(const float* __restrict__ hp,
                                             const int* __restrict__ srcrow,
                                             const int* __restrict__ start,
                                             const double* __restrict__ dinvd,
                                             float* __restrict__ out, int n) {
    int node = (int)((blockIdx.x * blockDim.x + threadIdx.x) >> 6);
    int lane = threadIdx.x & 63;
    if (node >= n) return;
    int s = start[node], e = start[node + 1];
    double dn = dinvd[node];
    const int f = lane * 2;
    float2 hs = *reinterpret_cast<const float2*>(hp + (size_t)node * D + f);
    double ax = 0.0, ay = 0.0;
    int p = s;
    for (; p + 16 <= e; p += 16) {
        int r[16]; float2 hv[16];
#pragma unroll
        for (int i = 0; i < 16; ++i) r[i] = srcrow[p + i];
#pragma unroll
        for (int i = 0; i < 16; ++i)
            hv[i] = *reinterpret_cast<const float2*>(hp + (size_t)r[i] * D + f);
#pragma unroll
        for (int i = 0; i < 16; ++i) { ax += (double)hv[i].x; ay += (double)hv[i].y; }
    }
    for (; p + 8 <= e; p += 8) {
        int r[8]; float2 hv[8];
#pragma unroll
        for (int i = 0; i < 8; ++i) r[i] = srcrow[p + i];
#pragma unroll
        for (int i = 0; i < 8; ++i)
            hv[i] = *reinterpret_cast<const float2*>(hp + (size_t)r[i] * D + f);
#pragma unroll
        for (int i = 0; i < 8; ++i) { ax += (double)hv[i].x; ay += (double)hv[i].y; }
    }
    for (; p < e; ++p) {
        int r = srcrow[p];
        float2 hv = *reinterpret_cast<const float2*>(hp + (size_t)r * D + f);
        ax += (double)hv.x; ay += (double)hv.y;
    }
    ax = dleaky((ax + (double)hs.x) * dn);
    ay = dleaky((ay + (double)hs.y) * dn);
    *reinterpret_cast<float2*>(out + (size_t)node * D + f) =
        make_float2((float)ax, (float)ay);
}

// ---------------- pool: block per graph over its contiguous node range ----------------
__global__ __launch_bounds__(256) void pool2(const double* __restrict__ s,
                                             const int* __restrict__ gstart,
                                             float* __restrict__ out) {
    __shared__ double lsum[256];
    const int g = blockIdx.x;
    const int tid = threadIdx.x;
    const int s0 = gstart[g], s1 = gstart[g + 1];
    double sum = 0.0;
    for (int i = s0 + tid; i < s1; i += 256) sum += s[i];
    lsum[tid] = sum;
    __syncthreads();
    for (int off = 128; off > 0; off >>= 1) {
        if (tid < off) lsum[tid] += lsum[tid + off];
        __syncthreads();
    }
    if (tid == 0) {
        int cnt = s1 - s0;
        out[g] = (float)(lsum[0] / (double)(cnt > 0 ? cnt : 1));
    }
}

extern "C" void kernel_launch(void* const* d_in, const int* in_sizes, int n_in,
                              void* d_out, int out_size, void* d_ws, size_t ws_size,
                              hipStream_t stream) {
    const float* x    = (const float*)d_in[0];
    const int*   eidx = (const int*)d_in[1];
    const int*   batch= (const int*)d_in[2];
    const float* W0   = (const float*)d_in[3];
    const float* W1   = (const float*)d_in[4];
    const float* W2   = (const float*)d_in[5];
    const float* Wfc1 = (const float*)d_in[6];
    const float* Wfc2 = (const float*)d_in[7];
    float* out = (float*)d_out;

    const int* erow = eidx;
    const int* ecol = eidx + N_EDGES;

    char* ws = (char*)d_ws;
    int*    hist   = (int*)   (ws + 0);
    int*    start  = (int*)   (ws + 200064);
    int*    cursor = (int*)   (ws + 400384);   // dead after build -> reused as gstart
    int*    bsum   = (int*)   (ws + 600448);
    double* dinvd  = (double*)(ws + 600704);
    int*    srcrow = (int*)   (ws + 1000704);
    double* svec   = (double*)(ws + 4200704);
    float*  bufA   = (float*) (ws + 4600832);
    float*  bufB   = (float*) (ws + 30200832);
    int*    gstart = cursor;

    hipMemsetAsync(hist, 0, (size_t)N_NODES * sizeof(int), stream);
    hist_kernel<<<(N_EDGES + 255) / 256, 256, 0, stream>>>(ecol, hist, N_EDGES);

    const int NB = (N_NODES + 1023) / 1024;  // 49
    scan1<<<NB, 256, 0, stream>>>(hist, start, bsum, dinvd, N_NODES);
    scan2<<<1, 256, 0, stream>>>(bsum, NB, start, N_NODES);
    scan3<<<NB, 256, 0, stream>>>(start, cursor, bsum, N_NODES);

    build_kernel<<<(N_EDGES + 255) / 256, 256, 0, stream>>>(erow, ecol, cursor, srcrow, N_EDGES);
    gbound_kernel<<<(N_NODES + 255) / 256, 256, 0, stream>>>(batch, gstart, N_NODES);

    const int GEMM_GRID = (N_NODES + 31) / 32;   // 1563
    const int AGG_GRID  = (N_NODES + 3) / 4;     // 12500

    // layers 0..2: gemm writes prescaled h' = dinv_r * (h @ W); agg_s finishes
    gemm128_mfma<<<GEMM_GRID, 256, 0, stream>>>(x, W0, bufA, N_NODES, 0, dinvd);
    agg_s<<<AGG_GRID, 256, 0, stream>>>(bufA, srcrow, start, dinvd, bufB, N_NODES);
    gemm128_mfma<<<GEMM_GRID, 256, 0, stream>>>(bufB, W1, bufA, N_NODES, 0, dinvd);
    agg_s<<<AGG_GRID, 256, 0, stream>>>(bufA, srcrow, start, dinvd, bufB, N_NODES);
    gemm128_mfma<<<GEMM_GRID, 256, 0, stream>>>(bufB, W2, bufA, N_NODES, 0, dinvd);
    agg_s<<<AGG_GRID, 256, 0, stream>>>(bufA, srcrow, start, dinvd, bufB, N_NODES);

    // fc1 + fc2 fused: svec = leaky(leaky(h@Wfc1) . wfc2)
    gemm_fc<<<GEMM_GRID, 256, 0, stream>>>(bufB, Wfc1, Wfc2, svec, N_NODES);

    pool2<<<NUM_GRAPHS, 256, 0, stream>>>(svec, gstart, out);
}